// Round 2
// baseline (1645.133 us; speedup 1.0000x reference)
//
#include <hip/hip_runtime.h>
#include <hip/hip_bf16.h>
#include <cstdio>
#include <cstdint>

using bf16 = __hip_bfloat16;
typedef __attribute__((ext_vector_type(8))) short bf16x8;   // MFMA A/B frag (8 bf16)
typedef __attribute__((ext_vector_type(4))) float f32x4;    // MFMA C/D frag / float4
typedef __attribute__((ext_vector_type(4))) unsigned int u32x4; // 16B chunk

#define HW   16384
#define KDIM 192

__device__ inline unsigned short f2bf(float x) {
  union { bf16 h; unsigned short u; } c;
  c.h = __float2bfloat16(x);
  return c.u;
}

// ---------------------------------------------------------------------------
// conv1x1 as GEMM: Out[b][o][n] = sum_c W[o][c] * X[b][c][n]
// W: fp32 [M][192] row-major (k-contiguous -> direct A staging, cvt to bf16)
// X: [b][192][HW], fp32 (first convs) or bf16 (proj). Pair-transpose staging.
// Tiles: BM=128, BN=128, BK=64 (3 k-tiles). 256 thr = 4 waves, wave-tile 64x64.
// ---------------------------------------------------------------------------
template <typename XT, typename OT>
__global__ __launch_bounds__(256, 3)
void gemm1x1(const float* __restrict__ W, const XT* __restrict__ X,
             OT* __restrict__ Out, int M) {
  const int n0 = blockIdx.x * 128;
  const int o0 = blockIdx.y * 128;
  const int b  = blockIdx.z;
  const XT* Xb = X + (size_t)b * KDIM * HW;
  OT* Ob = Out + (size_t)b * M * HW;

  __shared__ __align__(16) bf16 Asub[128][72];  // stride 144B = 36 dwords (== 4 mod 32)
  __shared__ __align__(16) bf16 Bsub[128][72];  // Bsub[n][k]

  const int t    = threadIdx.x;
  const int lane = t & 63;
  const int wave = t >> 6;
  const int wy   = wave >> 1;   // m half
  const int wx   = wave & 1;    // n half
  const int l16  = lane & 15;
  const int quad = lane >> 4;

  f32x4 acc[4][4];
  f32x4 zero = {0.f, 0.f, 0.f, 0.f};
#pragma unroll
  for (int i = 0; i < 4; ++i)
#pragma unroll
    for (int j = 0; j < 4; ++j) acc[i][j] = zero;

  for (int kt = 0; kt < 3; ++kt) {
    __syncthreads();
    // ---- stage A: rows o0..o0+127, k = kt*64..+63 (fp32 -> bf16) ----
    {
      const int seg = t & 7, rbase = t >> 3;
#pragma unroll
      for (int p = 0; p < 4; ++p) {
        int r = rbase + p * 32;
        int o = o0 + r;
        f32x4 f0 = zero, f1 = zero;
        if (o < M) {
          const float* src = W + (size_t)o * KDIM + kt * 64 + seg * 8;
          f0 = *(const f32x4*)(src);
          f1 = *(const f32x4*)(src + 4);
        }
        union { unsigned short us[8]; u32x4 v; } pk;
#pragma unroll
        for (int i = 0; i < 4; ++i) { pk.us[i] = f2bf(f0[i]); pk.us[4 + i] = f2bf(f1[i]); }
        *(u32x4*)(&Asub[r][seg * 8]) = pk.v;
      }
    }
    // ---- stage B with transpose: X[c][n] -> Bsub[n][k] via row pairs ----
    {
      const int nseg = t & 15;
      const int cp0  = t >> 4;   // 0..15
#pragma unroll
      for (int p = 0; p < 2; ++p) {
        int cpair = cp0 + p * 16;              // 0..31 -> k-local 2*cpair
        int c = kt * 64 + cpair * 2;
        unsigned short aa[8], bb[8];
        if constexpr (sizeof(XT) == 4) {
          const float* src = (const float*)Xb + (size_t)c * HW + n0 + nseg * 8;
          f32x4 a0 = *(const f32x4*)(src);
          f32x4 a1 = *(const f32x4*)(src + 4);
          f32x4 b0 = *(const f32x4*)(src + HW);
          f32x4 b1 = *(const f32x4*)(src + HW + 4);
#pragma unroll
          for (int i = 0; i < 4; ++i) {
            aa[i] = f2bf(a0[i]); aa[4 + i] = f2bf(a1[i]);
            bb[i] = f2bf(b0[i]); bb[4 + i] = f2bf(b1[i]);
          }
        } else {
          const bf16* src = (const bf16*)Xb + (size_t)c * HW + n0 + nseg * 8;
          u32x4 v0 = *(const u32x4*)(src);
          u32x4 v1 = *(const u32x4*)(src + HW);
          const unsigned short* pa = (const unsigned short*)&v0;
          const unsigned short* pb = (const unsigned short*)&v1;
#pragma unroll
          for (int i = 0; i < 8; ++i) { aa[i] = pa[i]; bb[i] = pb[i]; }
        }
#pragma unroll
        for (int s = 0; s < 8; ++s) {
          int j = (s + nseg + 2 * cpair) & 7;  // rotation: spread write banks
          unsigned int pack = (unsigned int)aa[j] | ((unsigned int)bb[j] << 16);
          *(unsigned int*)(&Bsub[nseg * 8 + j][cpair * 2]) = pack;
        }
      }
    }
    __syncthreads();
    // ---- compute: 2 k-steps of 32 ----
#pragma unroll
    for (int ks = 0; ks < 2; ++ks) {
      bf16x8 af[4], bfr[4];
      int koff = ks * 32 + quad * 8;
#pragma unroll
      for (int mi = 0; mi < 4; ++mi)
        af[mi] = *(const bf16x8*)(&Asub[wy * 64 + mi * 16 + l16][koff]);
#pragma unroll
      for (int ni = 0; ni < 4; ++ni)
        bfr[ni] = *(const bf16x8*)(&Bsub[wx * 64 + ni * 16 + l16][koff]);
#pragma unroll
      for (int mi = 0; mi < 4; ++mi)
#pragma unroll
        for (int ni = 0; ni < 4; ++ni)
          acc[mi][ni] = __builtin_amdgcn_mfma_f32_16x16x32_bf16(
              af[mi], bfr[ni], acc[mi][ni], 0, 0, 0);
    }
  }
  // ---- store: D elem (row=quad*4+r, col=l16) ----
#pragma unroll
  for (int mi = 0; mi < 4; ++mi)
#pragma unroll
    for (int ni = 0; ni < 4; ++ni)
#pragma unroll
      for (int r = 0; r < 4; ++r) {
        int o = o0 + wy * 64 + mi * 16 + quad * 4 + r;
        if (o < M) {
          int n = n0 + wx * 64 + ni * 16 + l16;
          float v = acc[mi][ni][r];
          if constexpr (sizeof(OT) == 4)
            Ob[(size_t)o * HW + n] = v;
          else
            Ob[(size_t)o * HW + n] = __float2bfloat16(v);
        }
      }
}

// ---------------------------------------------------------------------------
// depthwise 3x3, padding SAME, + optional sumsq(out) per channel for c<normLimit
// grid: (H/2, B*Cx), block 256 (2 rows x 128 cols). In/Out bf16, weights fp32.
// ---------------------------------------------------------------------------
__global__ void dwconv3(const bf16* __restrict__ In, const float* __restrict__ Wd,
                        bf16* __restrict__ Out, float* __restrict__ norm,
                        int Cx, int normLimit) {
  int bc = blockIdx.y;
  int c  = bc % Cx;
  int b  = bc / Cx;
  int h  = blockIdx.x * 2 + (threadIdx.x >> 7);
  int w  = threadIdx.x & 127;
  const bf16* I = In + (size_t)bc * HW;

  float wt[9];
#pragma unroll
  for (int i = 0; i < 9; ++i) wt[i] = Wd[c * 9 + i];

  float acc = 0.f;
#pragma unroll
  for (int dh = -1; dh <= 1; ++dh) {
    int hh = h + dh;
    if (hh < 0 || hh > 127) continue;
#pragma unroll
    for (int dw = -1; dw <= 1; ++dw) {
      int ww = w + dw;
      if (ww < 0 || ww > 127) continue;
      acc += wt[(dh + 1) * 3 + (dw + 1)] * __bfloat162float(I[hh * 128 + ww]);
    }
  }
  bf16 ob = __float2bfloat16(acc);
  Out[(size_t)bc * HW + h * 128 + w] = ob;

  if (c < normLimit) {
    float o = __bfloat162float(ob);   // rounded value: consistent with scores GEMM
    float s = o * o;
#pragma unroll
    for (int off = 32; off >= 1; off >>= 1) s += __shfl_down(s, off, 64);
    if ((threadIdx.x & 63) == 0) atomicAdd(&norm[b * KDIM + c], s);
  }
}

// ---------------------------------------------------------------------------
// scores split-K: S[bh][ci][cj] += sum_{n in chunk} q[ci][n]*k[cj][n]
// grid (16 kchunks, 32 bh), block 256. Each wave takes a 64-wide n slice.
// ---------------------------------------------------------------------------
__global__ __launch_bounds__(256, 2)
void scores_k(const bf16* __restrict__ QD, const bf16* __restrict__ KV,
              float* __restrict__ S) {
  int kc = blockIdx.x;
  int bh = blockIdx.y;
  int b = bh >> 2, h = bh & 3;
  const bf16* q = QD + ((size_t)b * KDIM + h * 48) * HW;
  const bf16* k = KV + ((size_t)b * (2 * KDIM) + h * 48) * HW;

  __shared__ __align__(16) char smem[2 * 48 * 264 * 2];
  bf16 (*Qs)[264] = (bf16(*)[264])smem;
  bf16 (*Ks)[264] = (bf16(*)[264])(smem + 48 * 264 * 2);
  float* Sred = (float*)smem;   // overlay (36864B <= 50688B), used after barrier

  const int t = threadIdx.x;
  const int lane = t & 63, wave = t >> 6;
  const int l16 = lane & 15, quad = lane >> 4;

  f32x4 acc[3][3];
  f32x4 zero = {0.f, 0.f, 0.f, 0.f};
#pragma unroll
  for (int i = 0; i < 3; ++i)
#pragma unroll
    for (int j = 0; j < 3; ++j) acc[i][j] = zero;

  for (int sc = 0; sc < 4; ++sc) {
    __syncthreads();
    int nb = kc * 1024 + sc * 256;
#pragma unroll
    for (int p = 0; p < 12; ++p) {
      int chunk = t + p * 256;          // 0..3071
      int row = chunk >> 5, seg = chunk & 31;
      const bf16* src = (row < 48 ? q + (size_t)row * HW
                                  : k + (size_t)(row - 48) * HW) + nb + seg * 8;
      u32x4 v = *(const u32x4*)src;
      bf16* dst = (row < 48) ? &Qs[row][seg * 8] : &Ks[row - 48][seg * 8];
      *(u32x4*)dst = v;
    }
    __syncthreads();
#pragma unroll
    for (int ks = 0; ks < 2; ++ks) {
      int koff = wave * 64 + ks * 32 + quad * 8;
      bf16x8 af[3], bfr[3];
#pragma unroll
      for (int mi = 0; mi < 3; ++mi) af[mi] = *(const bf16x8*)(&Qs[mi * 16 + l16][koff]);
#pragma unroll
      for (int ni = 0; ni < 3; ++ni) bfr[ni] = *(const bf16x8*)(&Ks[ni * 16 + l16][koff]);
#pragma unroll
      for (int mi = 0; mi < 3; ++mi)
#pragma unroll
        for (int ni = 0; ni < 3; ++ni)
          acc[mi][ni] = __builtin_amdgcn_mfma_f32_16x16x32_bf16(
              af[mi], bfr[ni], acc[mi][ni], 0, 0, 0);
    }
  }
  __syncthreads();
#pragma unroll
  for (int mi = 0; mi < 3; ++mi)
#pragma unroll
    for (int ni = 0; ni < 3; ++ni)
#pragma unroll
      for (int r = 0; r < 4; ++r) {
        int ci = mi * 16 + quad * 4 + r, cj = ni * 16 + l16;
        Sred[wave * 2304 + ci * 48 + cj] = acc[mi][ni][r];
      }
  __syncthreads();
#pragma unroll
  for (int p = 0; p < 9; ++p) {
    int idx = t + p * 256;
    float s = Sred[idx] + Sred[2304 + idx] + Sred[4608 + idx] + Sred[6912 + idx];
    atomicAdd(&S[(size_t)bh * 2304 + idx], s);
  }
}

// ---------------------------------------------------------------------------
// softmax over cj with l2-norm scaling + temperature. grid 1536 (bh*48), block 64.
// attn output padded [48][64] bf16 (zeros for cj>=48). temp fp32.
// ---------------------------------------------------------------------------
__global__ void softmax_k(const float* __restrict__ S, const float* __restrict__ nq2,
                          const float* __restrict__ nk2, const float* __restrict__ temp,
                          bf16* __restrict__ attn) {
  int blk = blockIdx.x;
  int bh = blk / 48, ci = blk % 48;
  int b = bh >> 2, h = bh & 3;
  int j = threadIdx.x;

  float tmp = temp[h];
  float qn = fmaxf(sqrtf(nq2[b * KDIM + h * 48 + ci]), 1e-12f);
  float val = -1e30f;
  if (j < 48) {
    float kn = fmaxf(sqrtf(nk2[b * KDIM + h * 48 + j]), 1e-12f);
    val = S[(size_t)bh * 2304 + ci * 48 + j] / (qn * kn) * tmp;
  }
  float m = val;
#pragma unroll
  for (int off = 32; off >= 1; off >>= 1) m = fmaxf(m, __shfl_xor(m, off, 64));
  float e = (j < 48) ? expf(val - m) : 0.f;
  float s = e;
#pragma unroll
  for (int off = 32; off >= 1; off >>= 1) s += __shfl_xor(s, off, 64);
  attn[(size_t)bh * 48 * 64 + ci * 64 + j] = __float2bfloat16((j < 48) ? (e / s) : 0.f);
}

// ---------------------------------------------------------------------------
// attn @ v : AO[b][h*48+ci][n] = sum_cj attn[bh][ci][cj] * v[cj][n]
// K padded to 64 (attn zeros + vT zero rows). grid (64 nchunks, 32 bh), block 256.
// ---------------------------------------------------------------------------
__global__ __launch_bounds__(256, 3)
void attnv_k(const bf16* __restrict__ attn, const bf16* __restrict__ KV,
             bf16* __restrict__ AO) {
  int nc = blockIdx.x, bh = blockIdx.y;
  int b = bh >> 2, h = bh & 3;
  int n0 = nc * 256;
  const bf16* v = KV + ((size_t)b * (2 * KDIM) + KDIM + h * 48) * HW;

  __shared__ __align__(16) bf16 vT[256][72];
  __shared__ __align__(16) bf16 At[48][72];

  const int t = threadIdx.x;
  const int lane = t & 63, wave = t >> 6;
  const int l16 = lane & 15, quad = lane >> 4;

  // stage attn [48][64] -> At
#pragma unroll
  for (int p = 0; p < 2; ++p) {
    int chunk = t + p * 256;
    if (chunk < 384) {
      int row = chunk >> 3, seg = chunk & 7;
      u32x4 x = *(const u32x4*)(attn + (size_t)bh * 3072 + row * 64 + seg * 8);
      *(u32x4*)(&At[row][seg * 8]) = x;
    }
  }
  // stage vT[n][cj] (cj 48..63 zero)
#pragma unroll
  for (int p = 0; p < 4; ++p) {
    int task = t + p * 256;            // 0..1023
    int cjp = task >> 5, ns8 = task & 31;
    int c0 = cjp * 2;
    u32x4 v0 = {0, 0, 0, 0}, v1 = {0, 0, 0, 0};
    if (c0 < 48)     v0 = *(const u32x4*)(v + (size_t)c0 * HW + n0 + ns8 * 8);
    if (c0 + 1 < 48) v1 = *(const u32x4*)(v + (size_t)(c0 + 1) * HW + n0 + ns8 * 8);
    const unsigned short* aa = (const unsigned short*)&v0;
    const unsigned short* bb = (const unsigned short*)&v1;
#pragma unroll
    for (int s = 0; s < 8; ++s) {
      int j = (s + ns8 + 2 * cjp) & 7;
      unsigned int pack = (unsigned int)aa[j] | ((unsigned int)bb[j] << 16);
      *(unsigned int*)(&vT[ns8 * 8 + j][c0]) = pack;
    }
  }
  __syncthreads();

  f32x4 acc[3][4];
  f32x4 zero = {0.f, 0.f, 0.f, 0.f};
#pragma unroll
  for (int i = 0; i < 3; ++i)
#pragma unroll
    for (int j = 0; j < 4; ++j) acc[i][j] = zero;

#pragma unroll
  for (int ks = 0; ks < 2; ++ks) {
    int koff = ks * 32 + quad * 8;
    bf16x8 af[3], bfr[4];
#pragma unroll
    for (int mi = 0; mi < 3; ++mi) af[mi] = *(const bf16x8*)(&At[mi * 16 + l16][koff]);
#pragma unroll
    for (int ni = 0; ni < 4; ++ni)
      bfr[ni] = *(const bf16x8*)(&vT[wave * 64 + ni * 16 + l16][koff]);
#pragma unroll
    for (int mi = 0; mi < 3; ++mi)
#pragma unroll
      for (int ni = 0; ni < 4; ++ni)
        acc[mi][ni] = __builtin_amdgcn_mfma_f32_16x16x32_bf16(
            af[mi], bfr[ni], acc[mi][ni], 0, 0, 0);
  }
  bf16* ao = AO + ((size_t)b * KDIM + h * 48) * HW;
#pragma unroll
  for (int mi = 0; mi < 3; ++mi)
#pragma unroll
    for (int ni = 0; ni < 4; ++ni)
#pragma unroll
      for (int r = 0; r < 4; ++r) {
        int ci = mi * 16 + quad * 4 + r;
        int n  = n0 + wave * 64 + ni * 16 + l16;
        ao[(size_t)ci * HW + n] = __float2bfloat16(acc[mi][ni][r]);
      }
}

// ---------------------------------------------------------------------------
extern "C" void kernel_launch(void* const* d_in, const int* in_sizes, int n_in,
                              void* d_out, int out_size, void* d_ws, size_t ws_size,
                              hipStream_t stream) {
  const float* x        = (const float*)d_in[0];
  const float* y        = (const float*)d_in[1];
  const float* w_qkv    = (const float*)d_in[2];
  const float* w_qkv_dw = (const float*)d_in[3];
  const float* w_query  = (const float*)d_in[4];
  const float* w_qry_dw = (const float*)d_in[5];
  const float* w_proj   = (const float*)d_in[6];
  const float* temp     = (const float*)d_in[7];
  float* out = (float*)d_out;

  char* ws = (char*)d_ws;
  size_t off = 0;
  auto alloc = [&](size_t bytes) -> char* {
    char* p = ws + off;
    off += (bytes + 255) & ~(size_t)255;
    return p;
  };
  bf16* kv_pre = (bf16*)alloc((size_t)8 * 384 * HW * 2);   // 100.7 MB
  bf16* kv     = (bf16*)alloc((size_t)8 * 384 * HW * 2);   // 100.7 MB
  bf16* q_pre  = (bf16*)alloc((size_t)8 * 192 * HW * 2);   // 50.3 MB (reused as AO)
  bf16* qd     = (bf16*)alloc((size_t)8 * 192 * HW * 2);   // 50.3 MB
  float* S     = (float*)alloc((size_t)32 * 2304 * 4);
  float* nq2   = (float*)alloc((size_t)8 * KDIM * 4);
  float* nk2   = (float*)alloc((size_t)8 * KDIM * 4);
  bf16* attn   = (bf16*)alloc((size_t)32 * 48 * 64 * 2);
  bf16* AO     = q_pre;  // q_pre dead after dwconv(q); AO written afterwards

  if (off > ws_size) {
    fprintf(stderr, "MDTA: workspace too small: need %zu, have %zu\n", off, ws_size);
    return;
  }

  hipMemsetAsync(S,   0, (size_t)32 * 2304 * 4, stream);
  hipMemsetAsync(nq2, 0, (size_t)8 * KDIM * 4, stream);
  hipMemsetAsync(nk2, 0, (size_t)8 * KDIM * 4, stream);

  // conv1x1 branches (fp32 in -> bf16 out)
  gemm1x1<float, bf16><<<dim3(128, 3, 8), 256, 0, stream>>>(w_qkv,   x, kv_pre, 384);
  gemm1x1<float, bf16><<<dim3(128, 2, 8), 256, 0, stream>>>(w_query, y, q_pre,  192);
  // depthwise 3x3 (+ sumsq for k-part and q)
  dwconv3<<<dim3(64, 8 * 384), 256, 0, stream>>>(kv_pre, w_qkv_dw, kv, nk2, 384, 192);
  dwconv3<<<dim3(64, 8 * 192), 256, 0, stream>>>(q_pre,  w_qry_dw, qd, nq2, 192, 192);
  // channel attention
  scores_k<<<dim3(16, 32), 256, 0, stream>>>(qd, kv, S);
  softmax_k<<<dim3(1536), 64, 0, stream>>>(S, nq2, nk2, temp, attn);
  attnv_k<<<dim3(64, 32), 256, 0, stream>>>(attn, kv, AO);
  // projection (bf16 in -> fp32 out)
  gemm1x1<bf16, float><<<dim3(128, 2, 8), 256, 0, stream>>>(w_proj, AO, out, 192);
}

// Round 3
// 585.740 us; speedup vs baseline: 2.8086x; 2.8086x over previous
//
#include <hip/hip_runtime.h>
#include <hip/hip_bf16.h>
#include <cstdio>
#include <cstdint>

using bf16 = __hip_bfloat16;
typedef __attribute__((ext_vector_type(8))) short bf16x8;   // MFMA A/B frag (8 bf16)
typedef __attribute__((ext_vector_type(4))) float f32x4;    // MFMA C/D frag / float4
typedef __attribute__((ext_vector_type(4))) unsigned int u32x4; // 16B chunk

#define HW   16384
#define KDIM 192

__device__ inline unsigned short f2bf(float x) {
  union { bf16 h; unsigned short u; } c;
  c.h = __float2bfloat16(x);
  return c.u;
}
__device__ inline float bf2f(unsigned short u) {
  union { float f; unsigned int i; } c;
  c.i = ((unsigned int)u) << 16;
  return c.f;
}

// ---------------------------------------------------------------------------
// conv1x1 as GEMM: Out[b][o][n] = sum_c W[o][c] * X[b][c][n]
// W: fp32 [M][192] row-major (k-contiguous -> direct A staging, cvt to bf16)
// X: [b][192][HW], fp32 (first convs) or bf16 (proj). Pair-transpose staging.
// Tiles: BM=128, BN=128, BK=64 (3 k-tiles). 256 thr = 4 waves, wave-tile 64x64.
// ---------------------------------------------------------------------------
template <typename XT, typename OT>
__global__ __launch_bounds__(256, 3)
void gemm1x1(const float* __restrict__ W, const XT* __restrict__ X,
             OT* __restrict__ Out, int M) {
  const int n0 = blockIdx.x * 128;
  const int o0 = blockIdx.y * 128;
  const int b  = blockIdx.z;
  const XT* Xb = X + (size_t)b * KDIM * HW;
  OT* Ob = Out + (size_t)b * M * HW;

  __shared__ __align__(16) bf16 Asub[128][72];  // stride 144B = 36 dwords (== 4 mod 32)
  __shared__ __align__(16) bf16 Bsub[128][72];  // Bsub[n][k]

  const int t    = threadIdx.x;
  const int lane = t & 63;
  const int wave = t >> 6;
  const int wy   = wave >> 1;   // m half
  const int wx   = wave & 1;    // n half
  const int l16  = lane & 15;
  const int quad = lane >> 4;

  f32x4 acc[4][4];
  f32x4 zero = {0.f, 0.f, 0.f, 0.f};
#pragma unroll
  for (int i = 0; i < 4; ++i)
#pragma unroll
    for (int j = 0; j < 4; ++j) acc[i][j] = zero;

  for (int kt = 0; kt < 3; ++kt) {
    __syncthreads();
    // ---- stage A: rows o0..o0+127, k = kt*64..+63 (fp32 -> bf16) ----
    {
      const int seg = t & 7, rbase = t >> 3;
#pragma unroll
      for (int p = 0; p < 4; ++p) {
        int r = rbase + p * 32;
        int o = o0 + r;
        f32x4 f0 = zero, f1 = zero;
        if (o < M) {
          const float* src = W + (size_t)o * KDIM + kt * 64 + seg * 8;
          f0 = *(const f32x4*)(src);
          f1 = *(const f32x4*)(src + 4);
        }
        union { unsigned short us[8]; u32x4 v; } pk;
#pragma unroll
        for (int i = 0; i < 4; ++i) { pk.us[i] = f2bf(f0[i]); pk.us[4 + i] = f2bf(f1[i]); }
        *(u32x4*)(&Asub[r][seg * 8]) = pk.v;
      }
    }
    // ---- stage B with transpose: X[c][n] -> Bsub[n][k] via row pairs ----
    {
      const int nseg = t & 15;
      const int cp0  = t >> 4;   // 0..15
#pragma unroll
      for (int p = 0; p < 2; ++p) {
        int cpair = cp0 + p * 16;              // 0..31 -> k-local 2*cpair
        int c = kt * 64 + cpair * 2;
        unsigned short aa[8], bb[8];
        if constexpr (sizeof(XT) == 4) {
          const float* src = (const float*)Xb + (size_t)c * HW + n0 + nseg * 8;
          f32x4 a0 = *(const f32x4*)(src);
          f32x4 a1 = *(const f32x4*)(src + 4);
          f32x4 b0 = *(const f32x4*)(src + HW);
          f32x4 b1 = *(const f32x4*)(src + HW + 4);
#pragma unroll
          for (int i = 0; i < 4; ++i) {
            aa[i] = f2bf(a0[i]); aa[4 + i] = f2bf(a1[i]);
            bb[i] = f2bf(b0[i]); bb[4 + i] = f2bf(b1[i]);
          }
        } else {
          const bf16* src = (const bf16*)Xb + (size_t)c * HW + n0 + nseg * 8;
          u32x4 v0 = *(const u32x4*)(src);
          u32x4 v1 = *(const u32x4*)(src + HW);
          const unsigned short* pa = (const unsigned short*)&v0;
          const unsigned short* pb = (const unsigned short*)&v1;
#pragma unroll
          for (int i = 0; i < 8; ++i) { aa[i] = pa[i]; bb[i] = pb[i]; }
        }
#pragma unroll
        for (int s = 0; s < 8; ++s) {
          int j = (s + nseg + 2 * cpair) & 7;  // rotation: spread write banks
          unsigned int pack = (unsigned int)aa[j] | ((unsigned int)bb[j] << 16);
          *(unsigned int*)(&Bsub[nseg * 8 + j][cpair * 2]) = pack;
        }
      }
    }
    __syncthreads();
    // ---- compute: 2 k-steps of 32 ----
#pragma unroll
    for (int ks = 0; ks < 2; ++ks) {
      bf16x8 af[4], bfr[4];
      int koff = ks * 32 + quad * 8;
#pragma unroll
      for (int mi = 0; mi < 4; ++mi)
        af[mi] = *(const bf16x8*)(&Asub[wy * 64 + mi * 16 + l16][koff]);
#pragma unroll
      for (int ni = 0; ni < 4; ++ni)
        bfr[ni] = *(const bf16x8*)(&Bsub[wx * 64 + ni * 16 + l16][koff]);
#pragma unroll
      for (int mi = 0; mi < 4; ++mi)
#pragma unroll
        for (int ni = 0; ni < 4; ++ni)
          acc[mi][ni] = __builtin_amdgcn_mfma_f32_16x16x32_bf16(
              af[mi], bfr[ni], acc[mi][ni], 0, 0, 0);
    }
  }
  // ---- store: D elem (row=quad*4+r, col=l16) ----
#pragma unroll
  for (int mi = 0; mi < 4; ++mi)
#pragma unroll
    for (int ni = 0; ni < 4; ++ni)
#pragma unroll
      for (int r = 0; r < 4; ++r) {
        int o = o0 + wy * 64 + mi * 16 + quad * 4 + r;
        if (o < M) {
          int n = n0 + wx * 64 + ni * 16 + l16;
          float v = acc[mi][ni][r];
          if constexpr (sizeof(OT) == 4)
            Ob[(size_t)o * HW + n] = v;
          else
            Ob[(size_t)o * HW + n] = __float2bfloat16(v);
        }
      }
}

// ---------------------------------------------------------------------------
// depthwise 3x3 v2: LDS-tiled. Block = one (b,c) image, 16-row x 128-col tile.
// Stage 18x128 halo tile with coalesced u32x4 loads (zero-filled halo rows),
// each thread computes 8 consecutive outputs from LDS (sliding window).
// + sumsq(out) per channel for c < normLimit (l2norm fused into softmax later).
// grid: (8, B*Cx), block 256.
// ---------------------------------------------------------------------------
template <int Cx>
__global__ __launch_bounds__(256)
void dwconv3(const bf16* __restrict__ In, const float* __restrict__ Wd,
             bf16* __restrict__ Out, float* __restrict__ norm, int normLimit) {
  const int bc = blockIdx.y;
  const int c  = bc % Cx;            // Cx is constexpr -> magic-mul
  const int b  = bc / Cx;
  const int h0 = blockIdx.x * 16;
  const bf16* I = In + (size_t)bc * HW;

  // rows 0..17 = image rows h0-1 .. h0+16; cols: [7]=0, [8..135]=data, [136]=0
  __shared__ __align__(16) unsigned short tile[18][144];

  const int t = threadIdx.x;
  // ---- stage: 288 chunks of 16B (18 rows x 16 chunks) ----
  {
    int r = t >> 4, ck = t & 15;
    int hh = h0 + r - 1;
    u32x4 v = {0, 0, 0, 0};
    if (hh >= 0 && hh < 128) v = *(const u32x4*)(I + hh * 128 + ck * 8);
    *(u32x4*)(&tile[r][8 + ck * 8]) = v;
  }
  if (t < 32) {            // remaining rows 16,17
    int task = 256 + t;
    int r = task >> 4, ck = task & 15;
    int hh = h0 + r - 1;
    u32x4 v = {0, 0, 0, 0};
    if (hh >= 0 && hh < 128) v = *(const u32x4*)(I + hh * 128 + ck * 8);
    *(u32x4*)(&tile[r][8 + ck * 8]) = v;
  } else if (t < 68) {     // zero edge columns: 18 rows x 2
    int z = t - 32;
    tile[z >> 1][(z & 1) ? 136 : 7] = 0;
  }

  float wt[9];
#pragma unroll
  for (int i = 0; i < 9; ++i) wt[i] = Wd[c * 9 + i];

  __syncthreads();

  // ---- compute: thread -> (row r, cols cb..cb+7) ----
  const int r  = t >> 4;          // 0..15
  const int cb = (t & 15) * 8;    // 0..120

  float acc[8];
#pragma unroll
  for (int o = 0; o < 8; ++o) acc[o] = 0.f;

#pragma unroll
  for (int rr = 0; rr < 3; ++rr) {
    const unsigned short* row = &tile[r + rr][7 + cb];
    float v[10];
#pragma unroll
    for (int j = 0; j < 10; ++j) v[j] = bf2f(row[j]);
    float w0 = wt[rr * 3 + 0], w1 = wt[rr * 3 + 1], w2 = wt[rr * 3 + 2];
#pragma unroll
    for (int o = 0; o < 8; ++o)
      acc[o] += w0 * v[o] + w1 * v[o + 1] + w2 * v[o + 2];
  }

  union { unsigned short us[8]; u32x4 v; } pk;
#pragma unroll
  for (int o = 0; o < 8; ++o) pk.us[o] = f2bf(acc[o]);
  *(u32x4*)(Out + (size_t)bc * HW + (h0 + r) * 128 + cb) = pk.v;

  if (c < normLimit) {
    float s = 0.f;
#pragma unroll
    for (int o = 0; o < 8; ++o) {
      float ov = bf2f(pk.us[o]);   // rounded value: consistent with scores GEMM
      s += ov * ov;
    }
#pragma unroll
    for (int off = 32; off >= 1; off >>= 1) s += __shfl_down(s, off, 64);
    if ((t & 63) == 0) atomicAdd(&norm[b * KDIM + c], s);
  }
}

// ---------------------------------------------------------------------------
// scores split-K: S[bh][ci][cj] += sum_{n in chunk} q[ci][n]*k[cj][n]
// grid (16 kchunks, 32 bh), block 256. Each wave takes a 64-wide n slice.
// ---------------------------------------------------------------------------
__global__ __launch_bounds__(256, 2)
void scores_k(const bf16* __restrict__ QD, const bf16* __restrict__ KV,
              float* __restrict__ S) {
  int kc = blockIdx.x;
  int bh = blockIdx.y;
  int b = bh >> 2, h = bh & 3;
  const bf16* q = QD + ((size_t)b * KDIM + h * 48) * HW;
  const bf16* k = KV + ((size_t)b * (2 * KDIM) + h * 48) * HW;

  __shared__ __align__(16) char smem[2 * 48 * 264 * 2];
  bf16 (*Qs)[264] = (bf16(*)[264])smem;
  bf16 (*Ks)[264] = (bf16(*)[264])(smem + 48 * 264 * 2);
  float* Sred = (float*)smem;   // overlay (36864B <= 50688B), used after barrier

  const int t = threadIdx.x;
  const int lane = t & 63, wave = t >> 6;
  const int l16 = lane & 15, quad = lane >> 4;

  f32x4 acc[3][3];
  f32x4 zero = {0.f, 0.f, 0.f, 0.f};
#pragma unroll
  for (int i = 0; i < 3; ++i)
#pragma unroll
    for (int j = 0; j < 3; ++j) acc[i][j] = zero;

  for (int sc = 0; sc < 4; ++sc) {
    __syncthreads();
    int nb = kc * 1024 + sc * 256;
#pragma unroll
    for (int p = 0; p < 12; ++p) {
      int chunk = t + p * 256;          // 0..3071
      int row = chunk >> 5, seg = chunk & 31;
      const bf16* src = (row < 48 ? q + (size_t)row * HW
                                  : k + (size_t)(row - 48) * HW) + nb + seg * 8;
      u32x4 v = *(const u32x4*)src;
      bf16* dst = (row < 48) ? &Qs[row][seg * 8] : &Ks[row - 48][seg * 8];
      *(u32x4*)dst = v;
    }
    __syncthreads();
#pragma unroll
    for (int ks = 0; ks < 2; ++ks) {
      int koff = wave * 64 + ks * 32 + quad * 8;
      bf16x8 af[3], bfr[3];
#pragma unroll
      for (int mi = 0; mi < 3; ++mi) af[mi] = *(const bf16x8*)(&Qs[mi * 16 + l16][koff]);
#pragma unroll
      for (int ni = 0; ni < 3; ++ni) bfr[ni] = *(const bf16x8*)(&Ks[ni * 16 + l16][koff]);
#pragma unroll
      for (int mi = 0; mi < 3; ++mi)
#pragma unroll
        for (int ni = 0; ni < 3; ++ni)
          acc[mi][ni] = __builtin_amdgcn_mfma_f32_16x16x32_bf16(
              af[mi], bfr[ni], acc[mi][ni], 0, 0, 0);
    }
  }
  __syncthreads();
#pragma unroll
  for (int mi = 0; mi < 3; ++mi)
#pragma unroll
    for (int ni = 0; ni < 3; ++ni)
#pragma unroll
      for (int r = 0; r < 4; ++r) {
        int ci = mi * 16 + quad * 4 + r, cj = ni * 16 + l16;
        Sred[wave * 2304 + ci * 48 + cj] = acc[mi][ni][r];
      }
  __syncthreads();
#pragma unroll
  for (int p = 0; p < 9; ++p) {
    int idx = t + p * 256;
    float s = Sred[idx] + Sred[2304 + idx] + Sred[4608 + idx] + Sred[6912 + idx];
    atomicAdd(&S[(size_t)bh * 2304 + idx], s);
  }
}

// ---------------------------------------------------------------------------
// softmax over cj with l2-norm scaling + temperature. grid 1536 (bh*48), block 64.
// attn output padded [48][64] bf16 (zeros for cj>=48). temp fp32.
// ---------------------------------------------------------------------------
__global__ void softmax_k(const float* __restrict__ S, const float* __restrict__ nq2,
                          const float* __restrict__ nk2, const float* __restrict__ temp,
                          bf16* __restrict__ attn) {
  int blk = blockIdx.x;
  int bh = blk / 48, ci = blk % 48;
  int b = bh >> 2, h = bh & 3;
  int j = threadIdx.x;

  float tmp = temp[h];
  float qn = fmaxf(sqrtf(nq2[b * KDIM + h * 48 + ci]), 1e-12f);
  float val = -1e30f;
  if (j < 48) {
    float kn = fmaxf(sqrtf(nk2[b * KDIM + h * 48 + j]), 1e-12f);
    val = S[(size_t)bh * 2304 + ci * 48 + j] / (qn * kn) * tmp;
  }
  float m = val;
#pragma unroll
  for (int off = 32; off >= 1; off >>= 1) m = fmaxf(m, __shfl_xor(m, off, 64));
  float e = (j < 48) ? expf(val - m) : 0.f;
  float s = e;
#pragma unroll
  for (int off = 32; off >= 1; off >>= 1) s += __shfl_xor(s, off, 64);
  attn[(size_t)bh * 48 * 64 + ci * 64 + j] = __float2bfloat16((j < 48) ? (e / s) : 0.f);
}

// ---------------------------------------------------------------------------
// attn @ v : AO[b][h*48+ci][n] = sum_cj attn[bh][ci][cj] * v[cj][n]
// K padded to 64 (attn zeros + vT zero rows). grid (64 nchunks, 32 bh), block 256.
// ---------------------------------------------------------------------------
__global__ __launch_bounds__(256, 3)
void attnv_k(const bf16* __restrict__ attn, const bf16* __restrict__ KV,
             bf16* __restrict__ AO) {
  int nc = blockIdx.x, bh = blockIdx.y;
  int b = bh >> 2, h = bh & 3;
  int n0 = nc * 256;
  const bf16* v = KV + ((size_t)b * (2 * KDIM) + KDIM + h * 48) * HW;

  __shared__ __align__(16) bf16 vT[256][72];
  __shared__ __align__(16) bf16 At[48][72];

  const int t = threadIdx.x;
  const int lane = t & 63, wave = t >> 6;
  const int l16 = lane & 15, quad = lane >> 4;

  // stage attn [48][64] -> At
#pragma unroll
  for (int p = 0; p < 2; ++p) {
    int chunk = t + p * 256;
    if (chunk < 384) {
      int row = chunk >> 3, seg = chunk & 7;
      u32x4 x = *(const u32x4*)(attn + (size_t)bh * 3072 + row * 64 + seg * 8);
      *(u32x4*)(&At[row][seg * 8]) = x;
    }
  }
  // stage vT[n][cj] (cj 48..63 zero)
#pragma unroll
  for (int p = 0; p < 4; ++p) {
    int task = t + p * 256;            // 0..1023
    int cjp = task >> 5, ns8 = task & 31;
    int c0 = cjp * 2;
    u32x4 v0 = {0, 0, 0, 0}, v1 = {0, 0, 0, 0};
    if (c0 < 48)     v0 = *(const u32x4*)(v + (size_t)c0 * HW + n0 + ns8 * 8);
    if (c0 + 1 < 48) v1 = *(const u32x4*)(v + (size_t)(c0 + 1) * HW + n0 + ns8 * 8);
    const unsigned short* aa = (const unsigned short*)&v0;
    const unsigned short* bb = (const unsigned short*)&v1;
#pragma unroll
    for (int s = 0; s < 8; ++s) {
      int j = (s + ns8 + 2 * cjp) & 7;
      unsigned int pack = (unsigned int)aa[j] | ((unsigned int)bb[j] << 16);
      *(unsigned int*)(&vT[ns8 * 8 + j][c0]) = pack;
    }
  }
  __syncthreads();

  f32x4 acc[3][4];
  f32x4 zero = {0.f, 0.f, 0.f, 0.f};
#pragma unroll
  for (int i = 0; i < 3; ++i)
#pragma unroll
    for (int j = 0; j < 4; ++j) acc[i][j] = zero;

#pragma unroll
  for (int ks = 0; ks < 2; ++ks) {
    int koff = ks * 32 + quad * 8;
    bf16x8 af[3], bfr[4];
#pragma unroll
    for (int mi = 0; mi < 3; ++mi) af[mi] = *(const bf16x8*)(&At[mi * 16 + l16][koff]);
#pragma unroll
    for (int ni = 0; ni < 4; ++ni)
      bfr[ni] = *(const bf16x8*)(&vT[wave * 64 + ni * 16 + l16][koff]);
#pragma unroll
    for (int mi = 0; mi < 3; ++mi)
#pragma unroll
      for (int ni = 0; ni < 4; ++ni)
        acc[mi][ni] = __builtin_amdgcn_mfma_f32_16x16x32_bf16(
            af[mi], bfr[ni], acc[mi][ni], 0, 0, 0);
  }
  bf16* ao = AO + ((size_t)b * KDIM + h * 48) * HW;
#pragma unroll
  for (int mi = 0; mi < 3; ++mi)
#pragma unroll
    for (int ni = 0; ni < 4; ++ni)
#pragma unroll
      for (int r = 0; r < 4; ++r) {
        int ci = mi * 16 + quad * 4 + r;
        int n  = n0 + wave * 64 + ni * 16 + l16;
        ao[(size_t)ci * HW + n] = __float2bfloat16(acc[mi][ni][r]);
      }
}

// ---------------------------------------------------------------------------
extern "C" void kernel_launch(void* const* d_in, const int* in_sizes, int n_in,
                              void* d_out, int out_size, void* d_ws, size_t ws_size,
                              hipStream_t stream) {
  const float* x        = (const float*)d_in[0];
  const float* y        = (const float*)d_in[1];
  const float* w_qkv    = (const float*)d_in[2];
  const float* w_qkv_dw = (const float*)d_in[3];
  const float* w_query  = (const float*)d_in[4];
  const float* w_qry_dw = (const float*)d_in[5];
  const float* w_proj   = (const float*)d_in[6];
  const float* temp     = (const float*)d_in[7];
  float* out = (float*)d_out;

  char* ws = (char*)d_ws;
  size_t off = 0;
  auto alloc = [&](size_t bytes) -> char* {
    char* p = ws + off;
    off += (bytes + 255) & ~(size_t)255;
    return p;
  };
  bf16* kv_pre = (bf16*)alloc((size_t)8 * 384 * HW * 2);   // 100.7 MB
  bf16* kv     = (bf16*)alloc((size_t)8 * 384 * HW * 2);   // 100.7 MB
  bf16* q_pre  = (bf16*)alloc((size_t)8 * 192 * HW * 2);   // 50.3 MB (reused as AO)
  bf16* qd     = (bf16*)alloc((size_t)8 * 192 * HW * 2);   // 50.3 MB
  float* S     = (float*)alloc((size_t)32 * 2304 * 4);
  float* nq2   = (float*)alloc((size_t)8 * KDIM * 4);
  float* nk2   = (float*)alloc((size_t)8 * KDIM * 4);
  bf16* attn   = (bf16*)alloc((size_t)32 * 48 * 64 * 2);
  bf16* AO     = q_pre;  // q_pre dead after dwconv(q); AO written afterwards

  if (off > ws_size) {
    fprintf(stderr, "MDTA: workspace too small: need %zu, have %zu\n", off, ws_size);
    return;
  }

  hipMemsetAsync(S,   0, (size_t)32 * 2304 * 4, stream);
  hipMemsetAsync(nq2, 0, (size_t)8 * KDIM * 4, stream);
  hipMemsetAsync(nk2, 0, (size_t)8 * KDIM * 4, stream);

  // conv1x1 branches (fp32 in -> bf16 out)
  gemm1x1<float, bf16><<<dim3(128, 3, 8), 256, 0, stream>>>(w_qkv,   x, kv_pre, 384);
  gemm1x1<float, bf16><<<dim3(128, 2, 8), 256, 0, stream>>>(w_query, y, q_pre,  192);
  // depthwise 3x3 (+ sumsq for k-part and q)
  dwconv3<384><<<dim3(8, 8 * 384), 256, 0, stream>>>(kv_pre, w_qkv_dw, kv, nk2, 192);
  dwconv3<192><<<dim3(8, 8 * 192), 256, 0, stream>>>(q_pre,  w_qry_dw, qd, nq2, 192);
  // channel attention
  scores_k<<<dim3(16, 32), 256, 0, stream>>>(qd, kv, S);
  softmax_k<<<dim3(1536), 64, 0, stream>>>(S, nq2, nk2, temp, attn);
  attnv_k<<<dim3(64, 32), 256, 0, stream>>>(attn, kv, AO);
  // projection (bf16 in -> fp32 out)
  gemm1x1<bf16, float><<<dim3(128, 2, 8), 256, 0, stream>>>(w_proj, AO, out, 192);
}